// Round 13
// baseline (162.000 us; speedup 1.0000x reference)
//
#include <hip/hip_runtime.h>
#include <hip/hip_bf16.h>

#define BB   2
#define NN   128
#define SS   4
#define DGG  8
#define CIN  4
#define COUT 8
#define HH   32
#define NT   256   // 4 waves/block, (256,4): the ONLY non-spilling config (R4/R5/R6/R8 mapped the wall)

// -1/ln2: all L1 weights/biases, b2, b3 are staged pre-multiplied by this so
// every MFMA outputs u = -pre_act/ln2, ready for exp2 directly (saves the
// per-silu input multiply).  W2/W3 stay unscaled (algebra: u2 = W2*v1 - b2/ln2).
#define SCN  (-1.44269504f)

typedef __attribute__((ext_vector_type(4))) float          fvec4;
typedef __attribute__((ext_vector_type(4))) unsigned short usvec4;
typedef __attribute__((ext_vector_type(8))) unsigned short usvec8;
typedef __attribute__((ext_vector_type(2))) __fp16         half2v;
typedef __attribute__((ext_vector_type(8))) __fp16         f16x8;
typedef __attribute__((ext_vector_type(4))) float          f32x4;
typedef __attribute__((ext_vector_type(4))) unsigned int   uvec4;

__device__ __forceinline__ float bf2f(unsigned short u) {
    return __uint_as_float(((unsigned int)u) << 16);
}
// silu in the exp2 domain: input u = -x/ln2 (produced by the scaled MFMA),
// output v = -silu(x)/ln2 = u * sigmoid(x).  2 trans + 2 VALU.
__device__ __forceinline__ float sil_u(float u) {
    float e = __builtin_amdgcn_exp2f(u);
    return u * __builtin_amdgcn_rcpf(1.0f + e);
}

__device__ __forceinline__ unsigned int pk2u(float a, float b) {
#if __has_builtin(__builtin_amdgcn_cvt_pkrtz)
    half2v h = __builtin_amdgcn_cvt_pkrtz(a, b);
#else
    half2v h; h[0] = (__fp16)a; h[1] = (__fp16)b;
#endif
    union { half2v h; unsigned int u; } x; x.h = h; return x.u;
}
union FU { uvec4 u; f16x8 h; };
__device__ __forceinline__ f16x8 mk_frag(unsigned a, unsigned b, unsigned c, unsigned d) {
    FU x; x.u = (uvec4){a, b, c, d}; return x.h;
}
__device__ __forceinline__ f16x8 mk_fragv(uvec4 u) {
    FU x; x.u = u; return x.h;
}
// sil_u + pack two f32x4 MFMA outputs into one B-fragment (j = 0..7)
__device__ __forceinline__ f16x8 sil_frag(f32x4 a, f32x4 b) {
    return mk_frag(pk2u(sil_u(a[0]), sil_u(a[1])),
                   pk2u(sil_u(a[2]), sil_u(a[3])),
                   pk2u(sil_u(b[0]), sil_u(b[1])),
                   pk2u(sil_u(b[2]), sil_u(b[3])));
}

__device__ __forceinline__ float loadS(const void* p, int idx, int fmode) {
    return fmode ? bf2f(((const unsigned short*)p)[idx])
                 : ((const float*)p)[idx];
}
__device__ __forceinline__ void load8(const void* p, int base, int fmode, float* dst) {
    if (fmode) {
        usvec8 v = *(const usvec8*)((const unsigned short*)p + base);
#pragma unroll
        for (int d = 0; d < 8; ++d) dst[d] = bf2f(v[d]);
    } else {
        fvec4 a = *(const fvec4*)((const float*)p + base);
        fvec4 b = *(const fvec4*)((const float*)p + base + 4);
        dst[0] = a[0]; dst[1] = a[1]; dst[2] = a[2]; dst[3] = a[3];
        dst[4] = b[0]; dst[5] = b[1]; dst[6] = b[2]; dst[7] = b[3];
    }
}
__device__ __forceinline__ int load_mask(const void* p, int idx, int mmode) {
    if (mmode == 0) return ((const int*)p)[idx] != 0;
    if (mmode == 1) return ((const unsigned short*)p)[idx] != 0;
    if (mmode == 2) return ((const unsigned char*)p)[idx] != 0;
    return ((const unsigned int*)p)[idx] != 0;
}
// scaled staging: every pair gets * sc while packing to f16
__device__ __forceinline__ void stage_pk(unsigned int* dst, const void* src,
                                         int pairs, int fmode, int tid, float sc) {
    if (fmode) {
        const unsigned short* s = (const unsigned short*)src;
        for (int x = tid; x < pairs; x += NT)
            dst[x] = pk2u(sc * bf2f(s[2 * x]), sc * bf2f(s[2 * x + 1]));
    } else {
        const float* s = (const float*)src;
        for (int x = tid; x < pairs; x += NT)
            dst[x] = pk2u(sc * s[2 * x], sc * s[2 * x + 1]);
    }
}
__device__ __forceinline__ void copy_arr(float* sm, const void* src, int off,
                                         int cnt, int fmode, int tid, float sc) {
    if (fmode) {
        const unsigned short* s = (const unsigned short*)src;
        for (int x = tid; x < cnt; x += NT) sm[off + x] = sc * bf2f(s[x]);
    } else {
        const float* s = (const float*)src;
        for (int x = tid; x < cnt; x += NT) sm[off + x] = sc * s[x];
    }
}
// modes: [0]=float dtype (0=f32,1=bf16), [1]=mask dtype (0=i32,1=bf16,2=u8,3=f32)
__device__ __forceinline__ void detect_inline(const void* g_mask, const void* g_coset,
                                              int tid, int* smi, int slot) {
    if (tid < 64) {
        const unsigned short* cu = (const unsigned short*)g_coset;
        unsigned short v = cu[2 * tid];
        int e = (v >> 7) & 0xFF;
        int hits = __popcll(__ballot(e >= 110 && e <= 135));
        int fmode_ = (hits > 32) ? 1 : 0;
        const unsigned short* mu = (const unsigned short*)g_mask;
        int evenBF = 0, any3 = 0, anyByte = 0;
        for (int r = 0; r < 8; ++r) {
            int idx = tid + r * 64;
            unsigned short m = mu[idx];
            if (m == 0x3F80) { any3 = 1; if (!(idx & 1)) evenBF = 1; }
            if (m == 0x0101 || m == 0x0100) anyByte = 1;
        }
        evenBF  = (__ballot(evenBF)  != 0ull);
        any3    = (__ballot(any3)    != 0ull);
        anyByte = (__ballot(anyByte) != 0ull);
        if (tid == 0) {
            smi[slot]     = fmode_;
            smi[slot + 1] = evenBF ? 1 : (any3 ? 3 : (anyByte ? 2 : 0));
        }
    }
}

// LDS layout (u32 units) — identical to R11/R12.
#define UG_G    0      // 2048: pairwise_g slice, packed f16 [pos][4]
#define F_FA    2048   // 2048 f32: coset b-slice [pos][ci]
#define U_YW1n  4096   // 512: [ci][32 rows][4]: SCN*(w0,w1), SCN*(b1y,0),0,0
#define U_GW1   4608   // 512: [ci][32 rows][4]: SCN*W1g row (8 f16)
#define U_GB1q  5120   // 512: [ci][32 rows][4]: SCN*(b1g,0),0,0,0 (k=8 bias col)
#define U_W2Y   5632   // 2048: pairs [ci][row][16] (UNSCALED)
#define U_W2G   7680   // 2048 (UNSCALED)
#define F_YB2   9728   // 128 f32 (SCN*b2y)
#define F_GB2   9856   // 128 f32 (SCN*b2g)
#define U_YW3   9984   // 64: pairs [ci][16] (UNSCALED)
#define U_GW3   10048  // 64 (UNSCALED)
#define F_YB3   10112  // 4 (SCN*b3y)
#define F_GB3   10116  // 4 (SCN*b3g)
#define U_CB1   10120  // 8: {pk(1,0),0,0,0} + 4 zeros (Zp region)
#define F_RED   10128  // 32: [wave(4)][ci][N,D]
#define F_MODE  10160  // 2
#define U_TOTAL 10162  // 40648 B -> 4 blocks/CU

// One block per (bn, s1); 256 threads = 4 waves; wave handles 8 position-
// tiles of 16 (pos = wave*128 + t*16 + col).
//
// ROUND 13: FULL 3-stage rotation.  R12's L1-only rotation gave just -2.3%
// (83.4us, VALUBusy still 65%): the L2->L3->exp tail chain remained serial
// within each iteration.  This round rotates every stage: iteration t runs
//   { tail(t) from carried L2-results -> L2(t+1) from carried L1-results
//     -> L1(t+2) from fresh LDS }
// — three mutually independent groups per iteration, serial chains span
// iterations.  SINGLE-ASSIGNMENT rotation: each carried var (r2*, d1*,
// fap0/fap1) is consumed-then-overwritten once per iteration -> no
// ping-pong, no unroll (stays clear of the R9/R10 compile-hang construct;
// both loops #pragma unroll 1).  +17 carried regs (~77 arch projected) on
// R12's 60.  Over-issued L1/L2 at t=8,9 read in-bounds LDS (max u32 idx
// 4223 < 10162); garbage/NaN terminates in dead registers.
// Gates: WRITE_SIZE in MBs (spill) -> revert to R12 and declare the
// register-capacity plateau; container-fail-twice -> same revert.
//
// Issue-floor arithmetic (R12 counters): busy 65% x 83.4 = 54us =~ 68 trans
// @~8cyc + ~115 VALU @2 + packs per iter.  Recoverable idle ~29us.
//
// Occupancy wall fully mapped (R4/R6/R8) -> 4 waves/SIMD structural.
// exp2-domain scaling verified (R11).  sigma row-permutation verified
// (R3-R12): sigma(4q+r) = 8q+r / 8q+4+r puts each MFMA's C output directly
// in the next layer's B-fragment layout; zero cross-lane ops.  Biases: b1y
// in A at k2 (B word1 = f16 1.0), b1g at k8 via quad-1 A rows + quad-1 B =
// {1,0,..}, b2 via MFMA C operand, b3 post-added in f32.  Quads 1-3 tail
// garbage never leaks (xor(1,2,4,8) stays in each 16-lane group; lane 0
// writes).
// NOTE: MFMA calls guarded by __HIP_DEVICE_COMPILE__ (host parse pass).
__global__ __launch_bounds__(NT, 4) void emha_mfma(
    const void* __restrict__ g_pw, const void* __restrict__ g_coset,
    const void* __restrict__ g_mask,
    const void* yW1, const void* yb1, const void* yW2, const void* yb2,
    const void* yW3, const void* yb3,
    const void* gW1, const void* gb1, const void* gW2, const void* gb2,
    const void* gW3, const void* gb3,
    const void* wout, void* outp)
{
    __shared__ __align__(16) unsigned int smu[U_TOTAL];
    float* smf = (float*)smu;
    int*   smi = (int*)smu;
    const int tid = threadIdx.x;

    detect_inline(g_mask, g_coset, tid, smi, F_MODE);
    __syncthreads();
    const int fmode = smi[F_MODE];
    const int mmode = smi[F_MODE + 1];
    __syncthreads();

    const int bn = blockIdx.x >> 2;   // b*128 + n1
    const int s1 = blockIdx.x & 3;
    const int b  = bn >> 7;
    const int n1 = bn & 127;

    // ---- stage pairwise_g slice (pos = n2*4+s2), packed f16 (raw) ----
#pragma unroll
    for (int it = 0; it < 2; ++it) {
        const int pos = tid + it * 256;
        const int n2 = pos >> 2, s2 = pos & 3;
        float g8[8];
        load8(g_pw, (((bn * NN + n2) * SS + s1) * SS + s2) * DGG, fmode, g8);
#pragma unroll
        for (int q = 0; q < 4; ++q)
            smu[UG_G + pos * 4 + q] = pk2u(g8[2 * q], g8[2 * q + 1]);
    }
    // ---- coset b-slice (f32, raw) ----
    for (int x = tid; x < 2048; x += NT)
        smf[F_FA + x] = loadS(g_coset, b * 2048 + x, fmode);
    // ---- L1 tables, SCN-scaled, bias columns folded ----
    for (int x = tid; x < 128; x += NT) {
        smu[U_YW1n + x * 4 + 0] = pk2u(SCN * loadS(yW1, 2 * x, fmode),
                                       SCN * loadS(yW1, 2 * x + 1, fmode));
        smu[U_YW1n + x * 4 + 1] = pk2u(SCN * loadS(yb1, x, fmode), 0.f);
        smu[U_YW1n + x * 4 + 2] = 0u;
        smu[U_YW1n + x * 4 + 3] = 0u;
        smu[U_GB1q + x * 4 + 0] = pk2u(SCN * loadS(gb1, x, fmode), 0.f);
        smu[U_GB1q + x * 4 + 1] = 0u;
        smu[U_GB1q + x * 4 + 2] = 0u;
        smu[U_GB1q + x * 4 + 3] = 0u;
    }
    stage_pk(&smu[U_GW1], gW1, 512,  fmode, tid, SCN);
    stage_pk(&smu[U_W2Y], yW2, 2048, fmode, tid, 1.0f);
    stage_pk(&smu[U_W2G], gW2, 2048, fmode, tid, 1.0f);
    stage_pk(&smu[U_YW3], yW3, 64,   fmode, tid, 1.0f);
    stage_pk(&smu[U_GW3], gW3, 64,   fmode, tid, 1.0f);
    copy_arr(smf, yb2, F_YB2, 128, fmode, tid, SCN);
    copy_arr(smf, gb2, F_GB2, 128, fmode, tid, SCN);
    copy_arr(smf, yb3, F_YB3, 4, fmode, tid, SCN);
    copy_arr(smf, gb3, F_GB3, 4, fmode, tid, SCN);
    if (tid < 8) smu[U_CB1 + tid] = (tid == 0) ? 0x00003C00u : 0u;  // pk(1,0), zeros

    // ---- key-mask bits -> 2x 64-bit SGPR sets per wave ----
    const int lane = tid & 63;
    const int wave = tid >> 6;        // 0..3; wave covers pos wave*128..+127
    const int mLo = load_mask(g_mask, b * 512 + wave * 128 + lane, mmode);
    const int mHi = load_mask(g_mask, b * 512 + wave * 128 + 64 + lane, mmode);
    const unsigned long long kmL = __ballot(mLo != 0);
    const unsigned long long kmH = __ballot(mHi != 0);
    __syncthreads();

    const int quad = lane >> 4;
    const int col  = lane & 15;
    const int qpos = n1 * 4 + s1;                    // query index in b-slice
    const int h0   = ((col >> 2) << 3) + (col & 3);  // sigma row for this lane
    const unsigned* Zp = &smu[U_CB1 + 4];            // 16B of zeros
    const f32x4 zf = {0.f, 0.f, 0.f, 0.f};

#pragma unroll 1
    for (int ci = 0; ci < CIN; ++ci) {
        const int rowy = (ci * 32 + h0) * 4;
        // L1 A-frags (SCN-scaled, bias folded; quads select k-range source)
        const f16x8 AY1a = mk_fragv(*(const uvec4*)((quad == 0) ? &smu[U_YW1n + rowy] : Zp));
        const f16x8 AY1b = mk_fragv(*(const uvec4*)((quad == 0) ? &smu[U_YW1n + rowy + 16] : Zp));
        const f16x8 GA = mk_fragv(*(const uvec4*)((quad == 0) ? &smu[U_GW1 + rowy]
                                   : (quad == 1) ? &smu[U_GB1q + rowy] : Zp));
        const f16x8 GB = mk_fragv(*(const uvec4*)((quad == 0) ? &smu[U_GW1 + rowy + 16]
                                   : (quad == 1) ? &smu[U_GB1q + rowy + 16] : Zp));
        // L2 A-frags (unscaled W2) + SCN*b2 C-operands (resident)
        const f16x8 Ay0 = mk_fragv(*(const uvec4*)&smu[U_W2Y + ci * 512 + h0 * 16 + quad * 4]);
        const f16x8 Ay1 = mk_fragv(*(const uvec4*)&smu[U_W2Y + ci * 512 + (h0 + 4) * 16 + quad * 4]);
        const f16x8 Ag0 = mk_fragv(*(const uvec4*)&smu[U_W2G + ci * 512 + h0 * 16 + quad * 4]);
        const f16x8 Ag1 = mk_fragv(*(const uvec4*)&smu[U_W2G + ci * 512 + (h0 + 4) * 16 + quad * 4]);
        const fvec4 cY0 = *(const fvec4*)&smf[F_YB2 + ci * 32 + quad * 8];
        const fvec4 cY1 = *(const fvec4*)&smf[F_YB2 + ci * 32 + quad * 8 + 4];
        const fvec4 cG0 = *(const fvec4*)&smf[F_GB2 + ci * 32 + quad * 8];
        const fvec4 cG1 = *(const fvec4*)&smf[F_GB2 + ci * 32 + quad * 8 + 4];
        // L3 A-frags (row 0 = w3 on col==0 lanes); C = zf, SCN*b3 post-added
        const f16x8 A3y = mk_fragv(*(const uvec4*)((col == 0) ? &smu[U_YW3 + ci * 16 + quad * 4] : Zp));
        const f16x8 A3g = mk_fragv(*(const uvec4*)((col == 0) ? &smu[U_GW3 + ci * 16 + quad * 4] : Zp));

        const float fb  = smf[F_FA + qpos * 4 + ci];
        const float b3y = smf[F_YB3 + ci];
        const float b3g = smf[F_GB3 + ci];

        // per-iter B sources: quad0 walks g; quad1 reads {1,0..} (bias col);
        // quads 2-3 read zeros (their A rows are zero anyway)
        const unsigned* pBg = (quad == 0) ? &smu[UG_G + (wave * 128 + col) * 4]
                            : ((quad == 1) ? &smu[U_CB1] : Zp);
        const int stepBg = (quad == 0) ? 64 : 0;
        const float* pFA = &smf[F_FA + (wave * 128 + col) * 4 + ci];

        // ---- pipeline prologue ----
        // L1(0) -> L2(0) results into carried r2*, then L1(1) into carried d1*
        float fap0 = *pFA;                 // fap[t]   (carried)
        f32x4 r2y0, r2y1, r2g0, r2g1;      // L2 results for tile t (carried)
        f32x4 d1a, d1b, dga, dgb;          // L1 results for tile t+1 (carried)
        {
            const uvec4 gq0 = *(const uvec4*)pBg;
            const f16x8 Bg10 = mk_fragv(gq0);
            const f16x8 B1y0 = mk_frag(pk2u(fap0, fb), 0x00003C00u, 0u, 0u);
            f32x4 t1a, t1b, tga, tgb;
#if defined(__HIP_DEVICE_COMPILE__)
            t1a = __builtin_amdgcn_mfma_f32_16x16x32_f16(AY1a, B1y0, zf, 0, 0, 0);
            t1b = __builtin_amdgcn_mfma_f32_16x16x32_f16(AY1b, B1y0, zf, 0, 0, 0);
            tga = __builtin_amdgcn_mfma_f32_16x16x32_f16(GA,   Bg10, zf, 0, 0, 0);
            tgb = __builtin_amdgcn_mfma_f32_16x16x32_f16(GB,   Bg10, zf, 0, 0, 0);
#else
            t1a = zf; t1b = zf; tga = zf; tgb = zf;  // host parse only
#endif
            const f16x8 By0 = sil_frag(t1a, t1b);
            const f16x8 Bg0 = sil_frag(tga, tgb);
#if defined(__HIP_DEVICE_COMPILE__)
            r2y0 = __builtin_amdgcn_mfma_f32_16x16x32_f16(Ay0, By0, cY0, 0, 0, 0);
            r2y1 = __builtin_amdgcn_mfma_f32_16x16x32_f16(Ay1, By0, cY1, 0, 0, 0);
            r2g0 = __builtin_amdgcn_mfma_f32_16x16x32_f16(Ag0, Bg0, cG0, 0, 0, 0);
            r2g1 = __builtin_amdgcn_mfma_f32_16x16x32_f16(Ag1, Bg0, cG1, 0, 0, 0);
#else
            r2y0 = cY0; r2y1 = cY1; r2g0 = cG0; r2g1 = cG1;  // host parse only
#endif
        }
        pBg += stepBg; pFA += 64;
        float fap1 = *pFA;                 // fap[t+1] (carried)
        {
            const uvec4 gq1 = *(const uvec4*)pBg;
            const f16x8 Bg11 = mk_fragv(gq1);
            const f16x8 B1y1 = mk_frag(pk2u(fap1, fb), 0x00003C00u, 0u, 0u);
#if defined(__HIP_DEVICE_COMPILE__)
            d1a = __builtin_amdgcn_mfma_f32_16x16x32_f16(AY1a, B1y1, zf, 0, 0, 0);
            d1b = __builtin_amdgcn_mfma_f32_16x16x32_f16(AY1b, B1y1, zf, 0, 0, 0);
            dga = __builtin_amdgcn_mfma_f32_16x16x32_f16(GA,   Bg11, zf, 0, 0, 0);
            dgb = __builtin_amdgcn_mfma_f32_16x16x32_f16(GB,   Bg11, zf, 0, 0, 0);
#else
            d1a = zf; d1b = zf; dga = zf; dgb = zf;  // host parse only
#endif
        }

        float aN = 0.f, aD = 0.f;
#pragma unroll 1
        for (int t = 0; t < 8; ++t) {
            // advance to t+2's operands (t>=6 over-reads stay inside smu)
            pBg += stepBg;
            pFA += 64;
            const uvec4 gq2 = *(const uvec4*)pBg;
            const float fap2 = *pFA;

            // ---- tail(t): consume carried L2 results ----
            const f16x8 By2 = sil_frag(r2y0, r2y1);  // v2 = -h2y/ln2
            const f16x8 Bg2 = sil_frag(r2g0, r2g1);
            f32x4 dy3, dg3;
#if defined(__HIP_DEVICE_COMPILE__)
            dy3 = __builtin_amdgcn_mfma_f32_16x16x32_f16(A3y, By2, zf, 0, 0, 0);
            dg3 = __builtin_amdgcn_mfma_f32_16x16x32_f16(A3g, Bg2, zf, 0, 0, 0);
#else
            dy3 = zf; dg3 = zf;  // host parse only
#endif
            const float v3y = sil_u(dy3[0] + b3y);
            const float v3g = sil_u(dg3[0] + b3g);
            const unsigned long long sel = (t < 4) ? kmL : kmH;  // t uniform
            const int kb = (int)((sel >> (((t & 3) << 4) + col)) & 1);
            const float e = kb ? __builtin_amdgcn_exp2f(-(v3y + v3g)) : 0.f;
            aD += e;
            aN += e * fap0;

            // ---- L2(t+1): consume carried L1 results, refill r2* ----
            const f16x8 By = sil_frag(d1a, d1b);     // v1 = -h1y/ln2
            const f16x8 Bg = sil_frag(dga, dgb);
#if defined(__HIP_DEVICE_COMPILE__)
            r2y0 = __builtin_amdgcn_mfma_f32_16x16x32_f16(Ay0, By, cY0, 0, 0, 0);
            r2y1 = __builtin_amdgcn_mfma_f32_16x16x32_f16(Ay1, By, cY1, 0, 0, 0);
            r2g0 = __builtin_amdgcn_mfma_f32_16x16x32_f16(Ag0, Bg, cG0, 0, 0, 0);
            r2g1 = __builtin_amdgcn_mfma_f32_16x16x32_f16(Ag1, Bg, cG1, 0, 0, 0);
#else
            r2y0 = cY0; r2y1 = cY1; r2g0 = cG0; r2g1 = cG1;  // host parse only
#endif

            // ---- L1(t+2): refill d1* (garbage past t=5 dies unread) ----
            {
                const f16x8 Bg1n = mk_fragv(gq2);
                const f16x8 B1yn = mk_frag(pk2u(fap2, fb), 0x00003C00u, 0u, 0u);
#if defined(__HIP_DEVICE_COMPILE__)
                d1a = __builtin_amdgcn_mfma_f32_16x16x32_f16(AY1a, B1yn, zf, 0, 0, 0);
                d1b = __builtin_amdgcn_mfma_f32_16x16x32_f16(AY1b, B1yn, zf, 0, 0, 0);
                dga = __builtin_amdgcn_mfma_f32_16x16x32_f16(GA,   Bg1n, zf, 0, 0, 0);
                dgb = __builtin_amdgcn_mfma_f32_16x16x32_f16(GB,   Bg1n, zf, 0, 0, 0);
#else
                d1a = zf; d1b = zf; dga = zf; dgb = zf;  // host parse only
#endif
            }

            // rotate fap
            fap0 = fap1;
            fap1 = fap2;
        }
        // reduce over the 16 positions (col bits, inside each 16-lane group)
        aN += __shfl_xor(aN, 1);  aD += __shfl_xor(aD, 1);
        aN += __shfl_xor(aN, 2);  aD += __shfl_xor(aD, 2);
        aN += __shfl_xor(aN, 4);  aD += __shfl_xor(aD, 4);
        aN += __shfl_xor(aN, 8);  aD += __shfl_xor(aD, 8);
        if (lane == 0) {
            smf[F_RED + (wave * 4 + ci) * 2 + 0] = aN;
            smf[F_RED + (wave * 4 + ci) * 2 + 1] = aD;
        }
    }
    __syncthreads();

    if (tid < COUT) {
        const int o = tid;
        const int m1 = load_mask(g_mask, b * 512 + qpos, mmode);
        float acc = 0.f;
#pragma unroll
        for (int ci = 0; ci < CIN; ++ci) {
            float N = 0.f, D = 0.f;
#pragma unroll
            for (int w = 0; w < 4; ++w) {
                N += smf[F_RED + (w * 4 + ci) * 2 + 0];
                D += smf[F_RED + (w * 4 + ci) * 2 + 1];
            }
            const float fbv = smf[F_FA + qpos * 4 + ci];
            const float cf = m1 ? (fbv + N / D) : 0.f;
            acc += cf * loadS(wout, o * CIN + ci, fmode);
        }
        const int oidx = (bn * SS + s1) * COUT + o;
        if (fmode) ((__hip_bfloat16*)outp)[oidx] = __float2bfloat16(acc);
        else       ((float*)outp)[oidx] = acc;
    }
}

extern "C" void kernel_launch(void* const* d_in, const int* in_sizes, int n_in,
                              void* d_out, int out_size, void* d_ws, size_t ws_size,
                              hipStream_t stream) {
    emha_mfma<<<BB * NN * SS, NT, 0, stream>>>(
        d_in[0], d_in[1], d_in[2],
        d_in[3], d_in[4], d_in[5], d_in[6], d_in[7], d_in[8],
        d_in[9], d_in[10], d_in[11], d_in[12], d_in[13], d_in[14],
        d_in[15], d_out);
}

// Round 14
// 159.141 us; speedup vs baseline: 1.0180x; 1.0180x over previous
//
#include <hip/hip_runtime.h>
#include <hip/hip_bf16.h>

#define BB   2
#define NN   128
#define SS   4
#define DGG  8
#define CIN  4
#define COUT 8
#define HH   32
#define NT   256   // 4 waves/block, (256,4): the ONLY non-spilling config (R4/R5/R6/R8 mapped the wall)

// -1/ln2: all L1 weights/biases, b2, b3 are staged pre-multiplied by this so
// every MFMA outputs u = -pre_act/ln2, ready for exp2 directly (saves the
// per-silu input multiply).  W2/W3 stay unscaled (algebra: u2 = W2*v1 - b2/ln2).
#define SCN  (-1.44269504f)

typedef __attribute__((ext_vector_type(4))) float          fvec4;
typedef __attribute__((ext_vector_type(4))) unsigned short usvec4;
typedef __attribute__((ext_vector_type(8))) unsigned short usvec8;
typedef __attribute__((ext_vector_type(2))) __fp16         half2v;
typedef __attribute__((ext_vector_type(8))) __fp16         f16x8;
typedef __attribute__((ext_vector_type(4))) float          f32x4;
typedef __attribute__((ext_vector_type(4))) unsigned int   uvec4;

__device__ __forceinline__ float bf2f(unsigned short u) {
    return __uint_as_float(((unsigned int)u) << 16);
}
// silu in the exp2 domain: input u = -x/ln2 (produced by the scaled MFMA),
// output v = -silu(x)/ln2 = u * sigmoid(x).  2 trans + 2 VALU.
__device__ __forceinline__ float sil_u(float u) {
    float e = __builtin_amdgcn_exp2f(u);
    return u * __builtin_amdgcn_rcpf(1.0f + e);
}

__device__ __forceinline__ unsigned int pk2u(float a, float b) {
#if __has_builtin(__builtin_amdgcn_cvt_pkrtz)
    half2v h = __builtin_amdgcn_cvt_pkrtz(a, b);
#else
    half2v h; h[0] = (__fp16)a; h[1] = (__fp16)b;
#endif
    union { half2v h; unsigned int u; } x; x.h = h; return x.u;
}
union FU { uvec4 u; f16x8 h; };
__device__ __forceinline__ f16x8 mk_frag(unsigned a, unsigned b, unsigned c, unsigned d) {
    FU x; x.u = (uvec4){a, b, c, d}; return x.h;
}
__device__ __forceinline__ f16x8 mk_fragv(uvec4 u) {
    FU x; x.u = u; return x.h;
}
// sil_u + pack two f32x4 MFMA outputs into one B-fragment (j = 0..7)
__device__ __forceinline__ f16x8 sil_frag(f32x4 a, f32x4 b) {
    return mk_frag(pk2u(sil_u(a[0]), sil_u(a[1])),
                   pk2u(sil_u(a[2]), sil_u(a[3])),
                   pk2u(sil_u(b[0]), sil_u(b[1])),
                   pk2u(sil_u(b[2]), sil_u(b[3])));
}

__device__ __forceinline__ float loadS(const void* p, int idx, int fmode) {
    return fmode ? bf2f(((const unsigned short*)p)[idx])
                 : ((const float*)p)[idx];
}
__device__ __forceinline__ void load8(const void* p, int base, int fmode, float* dst) {
    if (fmode) {
        usvec8 v = *(const usvec8*)((const unsigned short*)p + base);
#pragma unroll
        for (int d = 0; d < 8; ++d) dst[d] = bf2f(v[d]);
    } else {
        fvec4 a = *(const fvec4*)((const float*)p + base);
        fvec4 b = *(const fvec4*)((const float*)p + base + 4);
        dst[0] = a[0]; dst[1] = a[1]; dst[2] = a[2]; dst[3] = a[3];
        dst[4] = b[0]; dst[5] = b[1]; dst[6] = b[2]; dst[7] = b[3];
    }
}
__device__ __forceinline__ int load_mask(const void* p, int idx, int mmode) {
    if (mmode == 0) return ((const int*)p)[idx] != 0;
    if (mmode == 1) return ((const unsigned short*)p)[idx] != 0;
    if (mmode == 2) return ((const unsigned char*)p)[idx] != 0;
    return ((const unsigned int*)p)[idx] != 0;
}
// scaled staging: every pair gets * sc while packing to f16
__device__ __forceinline__ void stage_pk(unsigned int* dst, const void* src,
                                         int pairs, int fmode, int tid, float sc) {
    if (fmode) {
        const unsigned short* s = (const unsigned short*)src;
        for (int x = tid; x < pairs; x += NT)
            dst[x] = pk2u(sc * bf2f(s[2 * x]), sc * bf2f(s[2 * x + 1]));
    } else {
        const float* s = (const float*)src;
        for (int x = tid; x < pairs; x += NT)
            dst[x] = pk2u(sc * s[2 * x], sc * s[2 * x + 1]);
    }
}
__device__ __forceinline__ void copy_arr(float* sm, const void* src, int off,
                                         int cnt, int fmode, int tid, float sc) {
    if (fmode) {
        const unsigned short* s = (const unsigned short*)src;
        for (int x = tid; x < cnt; x += NT) sm[off + x] = sc * bf2f(s[x]);
    } else {
        const float* s = (const float*)src;
        for (int x = tid; x < cnt; x += NT) sm[off + x] = sc * s[x];
    }
}
// modes: [0]=float dtype (0=f32,1=bf16), [1]=mask dtype (0=i32,1=bf16,2=u8,3=f32)
__device__ __forceinline__ void detect_inline(const void* g_mask, const void* g_coset,
                                              int tid, int* smi, int slot) {
    if (tid < 64) {
        const unsigned short* cu = (const unsigned short*)g_coset;
        unsigned short v = cu[2 * tid];
        int e = (v >> 7) & 0xFF;
        int hits = __popcll(__ballot(e >= 110 && e <= 135));
        int fmode_ = (hits > 32) ? 1 : 0;
        const unsigned short* mu = (const unsigned short*)g_mask;
        int evenBF = 0, any3 = 0, anyByte = 0;
        for (int r = 0; r < 8; ++r) {
            int idx = tid + r * 64;
            unsigned short m = mu[idx];
            if (m == 0x3F80) { any3 = 1; if (!(idx & 1)) evenBF = 1; }
            if (m == 0x0101 || m == 0x0100) anyByte = 1;
        }
        evenBF  = (__ballot(evenBF)  != 0ull);
        any3    = (__ballot(any3)    != 0ull);
        anyByte = (__ballot(anyByte) != 0ull);
        if (tid == 0) {
            smi[slot]     = fmode_;
            smi[slot + 1] = evenBF ? 1 : (any3 ? 3 : (anyByte ? 2 : 0));
        }
    }
}

// LDS layout (u32 units) — identical to R11.
#define UG_G    0      // 2048: pairwise_g slice, packed f16 [pos][4]
#define F_FA    2048   // 2048 f32: coset b-slice [pos][ci]
#define U_YW1n  4096   // 512: [ci][32 rows][4]: SCN*(w0,w1), SCN*(b1y,0),0,0
#define U_GW1   4608   // 512: [ci][32 rows][4]: SCN*W1g row (8 f16)
#define U_GB1q  5120   // 512: [ci][32 rows][4]: SCN*(b1g,0),0,0,0 (k=8 bias col)
#define U_W2Y   5632   // 2048: pairs [ci][row][16] (UNSCALED)
#define U_W2G   7680   // 2048 (UNSCALED)
#define F_YB2   9728   // 128 f32 (SCN*b2y)
#define F_GB2   9856   // 128 f32 (SCN*b2g)
#define U_YW3   9984   // 64: pairs [ci][16] (UNSCALED)
#define U_GW3   10048  // 64 (UNSCALED)
#define F_YB3   10112  // 4 (SCN*b3y)
#define F_GB3   10116  // 4 (SCN*b3g)
#define U_CB1   10120  // 8: {pk(1,0),0,0,0} + 4 zeros (Zp region)
#define F_RED   10128  // 32: [wave(4)][ci][N,D]
#define F_MODE  10160  // 2
#define U_TOTAL 10162  // 40648 B -> 4 blocks/CU

// One block per (bn, s1); 256 threads = 4 waves; wave handles 8 position-
// tiles of 16 (pos = wave*128 + t*16 + col).
//
// ROUND 14 = REVERT TO R12 (the session optimum, 83.4us).  R13's full
// 3-stage rotation regressed to 86.5 (extra prologue/register overhead,
// zero idle recovered) — confirming the residual ~29us idle is NOT
// intra-wave chain latency.  Consolidated model: trans ops execute on the
// VALU pipe at quarter rate; per iteration 69 trans x 8cyc + ~115 VALU x
// 2cyc ~= 1000 busy-cyc; x128 iter/SIMD at load clock ~= 54us = measured
// 65% VALUBusy.  The 34 silu/lane/iter are algorithmic (dense hidden
// activations of both MLPs).  Filling the idle needs more waves — walled
// three ways (R4/R6: 64-reg budget spills; R8: 85-reg spills; 128-reg
// fits only 4 waves/SIMD).  R12's structure: L1 rotated one tile ahead
// (the only rotation depth that paid), SCN exp2-domain weight scaling,
// all biases folded into MFMA operands, mask in ballot'd SGPRs.
//
// sigma row-permutation (verified R3-R13): sigma(4q+r) = 8q+r / 8q+4+r puts
// each MFMA's C output directly in the next layer's B-fragment layout; zero
// cross-lane ops.  Biases: b1y in A at k2 (B word1 = f16 1.0), b1g at k8 via
// quad-1 A rows + quad-1 B = {1,0,..}, b2 via MFMA C operand, b3 post-added
// in f32.  Quads 1-3 tail garbage never leaks (xor(1,2,4,8) stays in each
// 16-lane group; lane 0 writes).
// NOTE: MFMA calls guarded by __HIP_DEVICE_COMPILE__ (host parse pass).
__global__ __launch_bounds__(NT, 4) void emha_mfma(
    const void* __restrict__ g_pw, const void* __restrict__ g_coset,
    const void* __restrict__ g_mask,
    const void* yW1, const void* yb1, const void* yW2, const void* yb2,
    const void* yW3, const void* yb3,
    const void* gW1, const void* gb1, const void* gW2, const void* gb2,
    const void* gW3, const void* gb3,
    const void* wout, void* outp)
{
    __shared__ __align__(16) unsigned int smu[U_TOTAL];
    float* smf = (float*)smu;
    int*   smi = (int*)smu;
    const int tid = threadIdx.x;

    detect_inline(g_mask, g_coset, tid, smi, F_MODE);
    __syncthreads();
    const int fmode = smi[F_MODE];
    const int mmode = smi[F_MODE + 1];
    __syncthreads();

    const int bn = blockIdx.x >> 2;   // b*128 + n1
    const int s1 = blockIdx.x & 3;
    const int b  = bn >> 7;
    const int n1 = bn & 127;

    // ---- stage pairwise_g slice (pos = n2*4+s2), packed f16 (raw) ----
#pragma unroll
    for (int it = 0; it < 2; ++it) {
        const int pos = tid + it * 256;
        const int n2 = pos >> 2, s2 = pos & 3;
        float g8[8];
        load8(g_pw, (((bn * NN + n2) * SS + s1) * SS + s2) * DGG, fmode, g8);
#pragma unroll
        for (int q = 0; q < 4; ++q)
            smu[UG_G + pos * 4 + q] = pk2u(g8[2 * q], g8[2 * q + 1]);
    }
    // ---- coset b-slice (f32, raw) ----
    for (int x = tid; x < 2048; x += NT)
        smf[F_FA + x] = loadS(g_coset, b * 2048 + x, fmode);
    // ---- L1 tables, SCN-scaled, bias columns folded ----
    for (int x = tid; x < 128; x += NT) {
        smu[U_YW1n + x * 4 + 0] = pk2u(SCN * loadS(yW1, 2 * x, fmode),
                                       SCN * loadS(yW1, 2 * x + 1, fmode));
        smu[U_YW1n + x * 4 + 1] = pk2u(SCN * loadS(yb1, x, fmode), 0.f);
        smu[U_YW1n + x * 4 + 2] = 0u;
        smu[U_YW1n + x * 4 + 3] = 0u;
        smu[U_GB1q + x * 4 + 0] = pk2u(SCN * loadS(gb1, x, fmode), 0.f);
        smu[U_GB1q + x * 4 + 1] = 0u;
        smu[U_GB1q + x * 4 + 2] = 0u;
        smu[U_GB1q + x * 4 + 3] = 0u;
    }
    stage_pk(&smu[U_GW1], gW1, 512,  fmode, tid, SCN);
    stage_pk(&smu[U_W2Y], yW2, 2048, fmode, tid, 1.0f);
    stage_pk(&smu[U_W2G], gW2, 2048, fmode, tid, 1.0f);
    stage_pk(&smu[U_YW3], yW3, 64,   fmode, tid, 1.0f);
    stage_pk(&smu[U_GW3], gW3, 64,   fmode, tid, 1.0f);
    copy_arr(smf, yb2, F_YB2, 128, fmode, tid, SCN);
    copy_arr(smf, gb2, F_GB2, 128, fmode, tid, SCN);
    copy_arr(smf, yb3, F_YB3, 4, fmode, tid, SCN);
    copy_arr(smf, gb3, F_GB3, 4, fmode, tid, SCN);
    if (tid < 8) smu[U_CB1 + tid] = (tid == 0) ? 0x00003C00u : 0u;  // pk(1,0), zeros

    // ---- key-mask bits -> 2x 64-bit SGPR sets per wave ----
    const int lane = tid & 63;
    const int wave = tid >> 6;        // 0..3; wave covers pos wave*128..+127
    const int mLo = load_mask(g_mask, b * 512 + wave * 128 + lane, mmode);
    const int mHi = load_mask(g_mask, b * 512 + wave * 128 + 64 + lane, mmode);
    const unsigned long long kmL = __ballot(mLo != 0);
    const unsigned long long kmH = __ballot(mHi != 0);
    __syncthreads();

    const int quad = lane >> 4;
    const int col  = lane & 15;
    const int qpos = n1 * 4 + s1;                    // query index in b-slice
    const int h0   = ((col >> 2) << 3) + (col & 3);  // sigma row for this lane
    const unsigned* Zp = &smu[U_CB1 + 4];            // 16B of zeros
    const f32x4 zf = {0.f, 0.f, 0.f, 0.f};

#pragma unroll 1
    for (int ci = 0; ci < CIN; ++ci) {
        const int rowy = (ci * 32 + h0) * 4;
        // L1 A-frags (SCN-scaled, bias folded; quads select k-range source)
        const f16x8 AY1a = mk_fragv(*(const uvec4*)((quad == 0) ? &smu[U_YW1n + rowy] : Zp));
        const f16x8 AY1b = mk_fragv(*(const uvec4*)((quad == 0) ? &smu[U_YW1n + rowy + 16] : Zp));
        const f16x8 GA = mk_fragv(*(const uvec4*)((quad == 0) ? &smu[U_GW1 + rowy]
                                   : (quad == 1) ? &smu[U_GB1q + rowy] : Zp));
        const f16x8 GB = mk_fragv(*(const uvec4*)((quad == 0) ? &smu[U_GW1 + rowy + 16]
                                   : (quad == 1) ? &smu[U_GB1q + rowy + 16] : Zp));
        // L2 A-frags (unscaled W2) + SCN*b2 C-operands (resident)
        const f16x8 Ay0 = mk_fragv(*(const uvec4*)&smu[U_W2Y + ci * 512 + h0 * 16 + quad * 4]);
        const f16x8 Ay1 = mk_fragv(*(const uvec4*)&smu[U_W2Y + ci * 512 + (h0 + 4) * 16 + quad * 4]);
        const f16x8 Ag0 = mk_fragv(*(const uvec4*)&smu[U_W2G + ci * 512 + h0 * 16 + quad * 4]);
        const f16x8 Ag1 = mk_fragv(*(const uvec4*)&smu[U_W2G + ci * 512 + (h0 + 4) * 16 + quad * 4]);
        const fvec4 cY0 = *(const fvec4*)&smf[F_YB2 + ci * 32 + quad * 8];
        const fvec4 cY1 = *(const fvec4*)&smf[F_YB2 + ci * 32 + quad * 8 + 4];
        const fvec4 cG0 = *(const fvec4*)&smf[F_GB2 + ci * 32 + quad * 8];
        const fvec4 cG1 = *(const fvec4*)&smf[F_GB2 + ci * 32 + quad * 8 + 4];
        // L3 A-frags (row 0 = w3 on col==0 lanes); C = zf, SCN*b3 post-added
        const f16x8 A3y = mk_fragv(*(const uvec4*)((col == 0) ? &smu[U_YW3 + ci * 16 + quad * 4] : Zp));
        const f16x8 A3g = mk_fragv(*(const uvec4*)((col == 0) ? &smu[U_GW3 + ci * 16 + quad * 4] : Zp));

        const float fb  = smf[F_FA + qpos * 4 + ci];
        const float b3y = smf[F_YB3 + ci];
        const float b3g = smf[F_GB3 + ci];

        // per-iter B sources: quad0 walks g; quad1 reads {1,0..} (bias col);
        // quads 2-3 read zeros (their A rows are zero anyway)
        const unsigned* pBg = (quad == 0) ? &smu[UG_G + (wave * 128 + col) * 4]
                            : ((quad == 1) ? &smu[U_CB1] : Zp);
        const int stepBg = (quad == 0) ? 64 : 0;
        const float* pFA = &smf[F_FA + (wave * 128 + col) * 4 + ci];

        // ---- pipeline prologue: issue tile t=0's L1 ----
        float fap_c = *pFA;
        f32x4 d1a, d1b, dga, dgb;
        {
            const uvec4 gq0 = *(const uvec4*)pBg;
            const f16x8 Bg1 = mk_fragv(gq0);
            const f16x8 B1y = mk_frag(pk2u(fap_c, fb), 0x00003C00u, 0u, 0u);
#if defined(__HIP_DEVICE_COMPILE__)
            d1a = __builtin_amdgcn_mfma_f32_16x16x32_f16(AY1a, B1y, zf, 0, 0, 0);
            d1b = __builtin_amdgcn_mfma_f32_16x16x32_f16(AY1b, B1y, zf, 0, 0, 0);
            dga = __builtin_amdgcn_mfma_f32_16x16x32_f16(GA,   Bg1, zf, 0, 0, 0);
            dgb = __builtin_amdgcn_mfma_f32_16x16x32_f16(GB,   Bg1, zf, 0, 0, 0);
#else
            d1a = zf; d1b = zf; dga = zf; dgb = zf;  // host parse only
#endif
        }

        float aN = 0.f, aD = 0.f;
#pragma unroll 1
        for (int t = 0; t < 8; ++t) {
            // next tile's operands (t=7 over-read stays inside smu)
            pBg += stepBg;
            pFA += 64;
            const uvec4 gqn = *(const uvec4*)pBg;
            const float fapn = *pFA;

            // consume tile t's L1 results
            const f16x8 By = sil_frag(d1a, d1b);   // v1 = -h1y/ln2 packed
            const f16x8 Bg = sil_frag(dga, dgb);   // v1 = -h1g/ln2 packed

            // issue tile t+1's L1 NOW (independent of t's L2/L3/tail) —
            // its LDS-read + MFMA latency hides under ~550cyc of t's work
            {
                const f16x8 Bg1n = mk_fragv(gqn);
                const f16x8 B1yn = mk_frag(pk2u(fapn, fb), 0x00003C00u, 0u, 0u);
#if defined(__HIP_DEVICE_COMPILE__)
                d1a = __builtin_amdgcn_mfma_f32_16x16x32_f16(AY1a, B1yn, zf, 0, 0, 0);
                d1b = __builtin_amdgcn_mfma_f32_16x16x32_f16(AY1b, B1yn, zf, 0, 0, 0);
                dga = __builtin_amdgcn_mfma_f32_16x16x32_f16(GA,   Bg1n, zf, 0, 0, 0);
                dgb = __builtin_amdgcn_mfma_f32_16x16x32_f16(GB,   Bg1n, zf, 0, 0, 0);
#else
                d1a = zf; d1b = zf; dga = zf; dgb = zf;  // host parse only
#endif
            }

            // tile t: L2 -> L3 -> tail
            f32x4 dy0, dy1, dg0, dg1, dy3, dg3;
#if defined(__HIP_DEVICE_COMPILE__)
            dy0 = __builtin_amdgcn_mfma_f32_16x16x32_f16(Ay0, By, cY0, 0, 0, 0);
            dy1 = __builtin_amdgcn_mfma_f32_16x16x32_f16(Ay1, By, cY1, 0, 0, 0);
            dg0 = __builtin_amdgcn_mfma_f32_16x16x32_f16(Ag0, Bg, cG0, 0, 0, 0);
            dg1 = __builtin_amdgcn_mfma_f32_16x16x32_f16(Ag1, Bg, cG1, 0, 0, 0);
#else
            dy0 = cY0; dy1 = cY1; dg0 = cG0; dg1 = cG1;  // host parse only
#endif
            const f16x8 By2 = sil_frag(dy0, dy1);  // v2 = -h2y/ln2
            const f16x8 Bg2 = sil_frag(dg0, dg1);

#if defined(__HIP_DEVICE_COMPILE__)
            dy3 = __builtin_amdgcn_mfma_f32_16x16x32_f16(A3y, By2, zf, 0, 0, 0);
            dg3 = __builtin_amdgcn_mfma_f32_16x16x32_f16(A3g, Bg2, zf, 0, 0, 0);
#else
            dy3 = zf; dg3 = zf;  // host parse only
#endif
            // u3 = W3*v2 + SCN*b3 = -(pre3)/ln2; v3 = -silu(pre3)/ln2;
            // e = exp(ky+kg) = exp2(-(v3y+v3g)).  Quad-0 lanes hold the
            // real dot in reg 0; quads 1-3 garbage never enters the reduce.
            const float v3y = sil_u(dy3[0] + b3y);
            const float v3g = sil_u(dg3[0] + b3g);
            const unsigned long long sel = (t < 4) ? kmL : kmH;  // t uniform
            const int kb = (int)((sel >> (((t & 3) << 4) + col)) & 1);
            const float e = kb ? __builtin_amdgcn_exp2f(-(v3y + v3g)) : 0.f;
            aD += e;
            aN += e * fap_c;

            fap_c = fapn;
        }
        // reduce over the 16 positions (col bits, inside each 16-lane group)
        aN += __shfl_xor(aN, 1);  aD += __shfl_xor(aD, 1);
        aN += __shfl_xor(aN, 2);  aD += __shfl_xor(aD, 2);
        aN += __shfl_xor(aN, 4);  aD += __shfl_xor(aD, 4);
        aN += __shfl_xor(aN, 8);  aD += __shfl_xor(aD, 8);
        if (lane == 0) {
            smf[F_RED + (wave * 4 + ci) * 2 + 0] = aN;
            smf[F_RED + (wave * 4 + ci) * 2 + 1] = aD;
        }
    }
    __syncthreads();

    if (tid < COUT) {
        const int o = tid;
        const int m1 = load_mask(g_mask, b * 512 + qpos, mmode);
        float acc = 0.f;
#pragma unroll
        for (int ci = 0; ci < CIN; ++ci) {
            float N = 0.f, D = 0.f;
#pragma unroll
            for (int w = 0; w < 4; ++w) {
                N += smf[F_RED + (w * 4 + ci) * 2 + 0];
                D += smf[F_RED + (w * 4 + ci) * 2 + 1];
            }
            const float fbv = smf[F_FA + qpos * 4 + ci];
            const float cf = m1 ? (fbv + N / D) : 0.f;
            acc += cf * loadS(wout, o * CIN + ci, fmode);
        }
        const int oidx = (bn * SS + s1) * COUT + o;
        if (fmode) ((__hip_bfloat16*)outp)[oidx] = __float2bfloat16(acc);
        else       ((float*)outp)[oidx] = acc;
    }
}

extern "C" void kernel_launch(void* const* d_in, const int* in_sizes, int n_in,
                              void* d_out, int out_size, void* d_ws, size_t ws_size,
                              hipStream_t stream) {
    emha_mfma<<<BB * NN * SS, NT, 0, stream>>>(
        d_in[0], d_in[1], d_in[2],
        d_in[3], d_in[4], d_in[5], d_in[6], d_in[7], d_in[8],
        d_in[9], d_in[10], d_in[11], d_in[12], d_in[13], d_in[14],
        d_in[15], d_out);
}